// Round 1
// baseline (486.133 us; speedup 1.0000x reference)
//
#include <hip/hip_runtime.h>
#include <hip/hip_bf16.h>
#include <cstdint>

#define BB   8
#define CCH  128
#define NND  16
#define HWD  3136      // 56*56
#define LLT  50176     // 16*3136
#define HWB  64        // hw columns per block (k1/k3); 3136 = 49*64
#define NHB  49

// workspace layout (float offsets)
#define OFF_S   0                       // 8*128*128   Gram (atomics, zeroed)
#define OFF_R   131072                  // 8*128       row sums (atomics, zeroed)
#define OFF_A   132096                  // 8*128*128   softmax(A)
#define OFF_M   263168                  // 8*128*128   M = A @ W_v
#define OFF_Q   394240                  // 8*128*128   Q = W_o @ M + I
#define OFF_AV  525312                  // 8*128       av = A @ b_v
#define OFF_CV  526336                  // 8*128       c = W_o av + b_o

// swap bit0<->bit4 of 5-bit quad index: both Gram-read sides become <=2-way
__device__ __forceinline__ int swz(int q){
  return (q & 0x0E) | ((q & 1) << 4) | ((q >> 4) & 1);
}

// ---------------- k1: fused Gram + rowsum + Y(=mean_N x) --------------------
__global__ __launch_bounds__(256) void k1_stats(const float* __restrict__ x,
    float* __restrict__ S, float* __restrict__ r, float* __restrict__ Y)
{
  __shared__ float xt[HWB][CCH];              // transposed tile [hw][c], quad-swizzled
  const int b   = blockIdx.x / NHB;
  const int hb  = blockIdx.x % NHB;
  const int hw0 = hb * HWB;
  const int tid = threadIdx.x;
  const int tx  = tid & 15, ty = tid >> 4;

  float acc[8][8];
  float yac[8][4];
  #pragma unroll
  for(int i=0;i<8;i++){
    #pragma unroll
    for(int j=0;j<8;j++) acc[i][j]=0.f;
    #pragma unroll
    for(int j=0;j<4;j++) yac[i][j]=0.f;
  }

  const float* xb = x + (size_t)b*CCH*LLT;
  const int qa0 = swz(2*ty  )<<2, qa1 = swz(2*ty+1)<<2;
  const int qb0 = swz(2*tx  )<<2, qb1 = swz(2*tx+1)<<2;

  for(int n=0;n<NND;n++){
    __syncthreads();                          // protect prior reads
    #pragma unroll
    for(int it=0; it<8; it++){
      const int cc = (tid>>4) + 16*it;        // row (channel)
      const float4 v = *reinterpret_cast<const float4*>(
          xb + (size_t)cc*LLT + n*HWD + hw0 + 4*tx);
      const int pc = (swz(cc>>2)<<2) | (cc&3);
      xt[4*tx+0][pc] = v.x;
      xt[4*tx+1][pc] = v.y;
      xt[4*tx+2][pc] = v.z;
      xt[4*tx+3][pc] = v.w;
    }
    __syncthreads();
    for(int l=0;l<HWB;l++){
      const float* row = xt[l];
      float4 A0 = *(const float4*)(row + qa0);
      float4 A1 = *(const float4*)(row + qa1);
      float4 B0 = *(const float4*)(row + qb0);
      float4 B1 = *(const float4*)(row + qb1);
      float av_[8] = {A0.x,A0.y,A0.z,A0.w,A1.x,A1.y,A1.z,A1.w};
      float bv_[8] = {B0.x,B0.y,B0.z,B0.w,B1.x,B1.y,B1.z,B1.w};
      #pragma unroll
      for(int i=0;i<8;i++)
        #pragma unroll
        for(int j=0;j<8;j++)
          acc[i][j] = fmaf(av_[i], bv_[j], acc[i][j]);
    }
    // Y accumulation: c = 8*ty+i, hw = 4*tx+j
    #pragma unroll
    for(int j=0;j<4;j++){
      const float* row = xt[4*tx+j];
      float4 V0 = *(const float4*)(row + qa0);
      float4 V1 = *(const float4*)(row + qa1);
      yac[0][j]+=V0.x; yac[1][j]+=V0.y; yac[2][j]+=V0.z; yac[3][j]+=V0.w;
      yac[4][j]+=V1.x; yac[5][j]+=V1.y; yac[6][j]+=V1.z; yac[7][j]+=V1.w;
    }
  }
  // write Y = sum/16
  #pragma unroll
  for(int i=0;i<8;i++){
    float4 o4 = make_float4(yac[i][0]*0.0625f, yac[i][1]*0.0625f,
                            yac[i][2]*0.0625f, yac[i][3]*0.0625f);
    *reinterpret_cast<float4*>(Y + ((size_t)b*CCH + 8*ty+i)*HWD + hw0 + 4*tx) = o4;
  }
  // r: reduce across the 16 tx lanes then one atomic per row
  #pragma unroll
  for(int i=0;i<8;i++){
    float p = yac[i][0]+yac[i][1]+yac[i][2]+yac[i][3];
    #pragma unroll
    for(int s=1;s<16;s<<=1) p += __shfl_xor(p, s, 16);
    if(tx==0) atomicAdd(&r[b*CCH + 8*ty+i], p);
  }
  // S partial -> atomics
  #pragma unroll
  for(int i=0;i<8;i++)
    #pragma unroll
    for(int j=0;j<8;j++)
      atomicAdd(&S[(size_t)b*CCH*CCH + (size_t)(8*ty+i)*CCH + 8*tx+j], acc[i][j]);
}

// ---------------- k2a: G = WqSWk^T + bias terms, softmax -> A, av -----------
__global__ __launch_bounds__(256) void k2a(const float* __restrict__ S, const float* __restrict__ r,
    const float* __restrict__ wq, const float* __restrict__ bq,
    const float* __restrict__ wk, const float* __restrict__ bk,
    const float* __restrict__ bv,
    float* __restrict__ A, float* __restrict__ av)
{
  __shared__ float t1[16][132];     // padded: conflict-free f4 reads
  __shared__ float wrk_s[CCH];
  __shared__ float wrq_s[16];
  const int b   = blockIdx.x >> 3;
  const int r0  = (blockIdx.x & 7) * 16;
  const int tid = threadIdx.x;
  const float* Sb = S + (size_t)b*CCH*CCH;
  const float* rb = r + b*CCH;

  if(tid < CCH){
    float s = 0.f;
    for(int m=0;m<CCH;m++) s += wk[(size_t)tid*CCH+m]*rb[m];
    wrk_s[tid] = s;
  } else if(tid < CCH+16){
    const int rr2 = tid - CCH;
    float s = 0.f;
    for(int m=0;m<CCH;m++) s += wq[(size_t)(r0+rr2)*CCH+m]*rb[m];
    wrq_s[rr2] = s;
  }

  const int rr = tid >> 4;            // 0..15 local row
  const int c0 = (tid & 15) * 8;
  { // T1 = W_q[rows] @ S  (S from L2, row-streamed)
    float a8[8] = {0,0,0,0,0,0,0,0};
    const float* wqr = wq + (size_t)(r0+rr)*CCH;
    for(int m4=0;m4<32;m4++){
      float4 w4 = *(const float4*)(wqr + 4*m4);
      const float wl[4] = {w4.x,w4.y,w4.z,w4.w};
      #pragma unroll
      for(int mm=0;mm<4;mm++){
        const int m = 4*m4+mm;
        const float w = wl[mm];
        float4 s0 = *(const float4*)(Sb + (size_t)m*CCH + c0);
        float4 s1 = *(const float4*)(Sb + (size_t)m*CCH + c0 + 4);
        a8[0]=fmaf(w,s0.x,a8[0]); a8[1]=fmaf(w,s0.y,a8[1]);
        a8[2]=fmaf(w,s0.z,a8[2]); a8[3]=fmaf(w,s0.w,a8[3]);
        a8[4]=fmaf(w,s1.x,a8[4]); a8[5]=fmaf(w,s1.y,a8[5]);
        a8[6]=fmaf(w,s1.z,a8[6]); a8[7]=fmaf(w,s1.w,a8[7]);
      }
    }
    #pragma unroll
    for(int j=0;j<8;j++) t1[rr][c0+j] = a8[j];
  }
  __syncthreads();

  const int j0 = (tid & 15) * 8;
  float g[8] = {0,0,0,0,0,0,0,0};
  for(int c4=0;c4<32;c4++){
    float4 tv = *(const float4*)(&t1[rr][4*c4]);
    #pragma unroll
    for(int jj=0;jj<8;jj++){
      float4 w4 = *(const float4*)(wk + (size_t)(j0+jj)*CCH + 4*c4);
      g[jj]=fmaf(tv.x,w4.x,g[jj]); g[jj]=fmaf(tv.y,w4.y,g[jj]);
      g[jj]=fmaf(tv.z,w4.z,g[jj]); g[jj]=fmaf(tv.w,w4.w,g[jj]);
    }
  }
  const float bqr  = bq[r0+rr];
  const float wrqr = wrq_s[rr];
  #pragma unroll
  for(int jj=0;jj<8;jj++)
    g[jj] += wrqr*bk[j0+jj] + bqr*wrk_s[j0+jj] + (float)LLT*bqr*bk[j0+jj];

  // softmax across the 16-lane row group
  float mx = g[0];
  #pragma unroll
  for(int jj=1;jj<8;jj++) mx = fmaxf(mx, g[jj]);
  #pragma unroll
  for(int s=1;s<16;s<<=1) mx = fmaxf(mx, __shfl_xor(mx, s, 16));
  float ex[8], sum=0.f;
  #pragma unroll
  for(int jj=0;jj<8;jj++){ ex[jj] = expf(g[jj]-mx); sum += ex[jj]; }
  #pragma unroll
  for(int s=1;s<16;s<<=1) sum += __shfl_xor(sum, s, 16);
  const float inv = 1.0f/sum;

  float* Arow = A + ((size_t)b*CCH + r0+rr)*CCH + j0;
  *(float4*)(Arow  ) = make_float4(ex[0]*inv, ex[1]*inv, ex[2]*inv, ex[3]*inv);
  *(float4*)(Arow+4) = make_float4(ex[4]*inv, ex[5]*inv, ex[6]*inv, ex[7]*inv);

  float pa = 0.f;
  #pragma unroll
  for(int jj=0;jj<8;jj++) pa += ex[jj]*inv*bv[j0+jj];
  #pragma unroll
  for(int s=1;s<16;s<<=1) pa += __shfl_xor(pa, s, 16);
  if((tid&15)==0) av[b*CCH + r0+rr] = pa;
}

// ---------------- k2b: M = A @ W_v ------------------------------------------
__global__ __launch_bounds__(256) void k2b(const float* __restrict__ A,
    const float* __restrict__ wv, float* __restrict__ M)
{
  const int b  = blockIdx.x >> 3;
  const int r0 = (blockIdx.x & 7)*16;
  const int tid = threadIdx.x;
  const int rr = tid>>4, c0 = (tid&15)*8;
  const float* Ar = A + ((size_t)b*CCH + r0+rr)*CCH;
  float a8[8] = {0,0,0,0,0,0,0,0};
  for(int k4=0;k4<32;k4++){
    float4 a4 = *(const float4*)(Ar + 4*k4);
    const float al[4] = {a4.x,a4.y,a4.z,a4.w};
    #pragma unroll
    for(int kk=0;kk<4;kk++){
      const int k = 4*k4+kk;
      const float w = al[kk];
      float4 v0 = *(const float4*)(wv + (size_t)k*CCH + c0);
      float4 v1 = *(const float4*)(wv + (size_t)k*CCH + c0 + 4);
      a8[0]=fmaf(w,v0.x,a8[0]); a8[1]=fmaf(w,v0.y,a8[1]);
      a8[2]=fmaf(w,v0.z,a8[2]); a8[3]=fmaf(w,v0.w,a8[3]);
      a8[4]=fmaf(w,v1.x,a8[4]); a8[5]=fmaf(w,v1.y,a8[5]);
      a8[6]=fmaf(w,v1.z,a8[6]); a8[7]=fmaf(w,v1.w,a8[7]);
    }
  }
  float* Mr = M + ((size_t)b*CCH + r0+rr)*CCH + c0;
  *(float4*)(Mr  ) = make_float4(a8[0],a8[1],a8[2],a8[3]);
  *(float4*)(Mr+4) = make_float4(a8[4],a8[5],a8[6],a8[7]);
}

// ---------------- k2c: Q = W_o @ M + I ;  c = W_o av + b_o ------------------
__global__ __launch_bounds__(256) void k2c(const float* __restrict__ M,
    const float* __restrict__ wo, const float* __restrict__ bo,
    const float* __restrict__ av, float* __restrict__ Q, float* __restrict__ cv)
{
  const int b  = blockIdx.x >> 3;
  const int o0 = (blockIdx.x & 7)*16;
  const int tid = threadIdx.x;
  const int rr = tid>>4, c0 = (tid&15)*8;
  const int o  = o0 + rr;
  const float* wor = wo + (size_t)o*CCH;
  const float* Mb  = M + (size_t)b*CCH*CCH;
  float a8[8] = {0,0,0,0,0,0,0,0};
  for(int m4=0;m4<32;m4++){
    float4 w4 = *(const float4*)(wor + 4*m4);
    const float wl[4] = {w4.x,w4.y,w4.z,w4.w};
    #pragma unroll
    for(int mm=0;mm<4;mm++){
      const int m = 4*m4+mm;
      const float w = wl[mm];
      float4 v0 = *(const float4*)(Mb + (size_t)m*CCH + c0);
      float4 v1 = *(const float4*)(Mb + (size_t)m*CCH + c0 + 4);
      a8[0]=fmaf(w,v0.x,a8[0]); a8[1]=fmaf(w,v0.y,a8[1]);
      a8[2]=fmaf(w,v0.z,a8[2]); a8[3]=fmaf(w,v0.w,a8[3]);
      a8[4]=fmaf(w,v1.x,a8[4]); a8[5]=fmaf(w,v1.y,a8[5]);
      a8[6]=fmaf(w,v1.z,a8[6]); a8[7]=fmaf(w,v1.w,a8[7]);
    }
  }
  #pragma unroll
  for(int j=0;j<8;j++) if(o == c0+j) a8[j] += 1.0f;   // +I (residual folded)
  float* Qr = Q + ((size_t)b*CCH + o)*CCH + c0;
  *(float4*)(Qr  ) = make_float4(a8[0],a8[1],a8[2],a8[3]);
  *(float4*)(Qr+4) = make_float4(a8[4],a8[5],a8[6],a8[7]);

  if(tid < 16){
    const int oo = o0 + tid;
    float s = 0.f;
    for(int m=0;m<CCH;m++) s += wo[(size_t)oo*CCH+m]*av[b*CCH+m];
    cv[b*CCH + oo] = s + bo[oo];
  }
}

// ---------------- k3: out = Q @ Y + c  (in place over Y kept in d_out) ------
__global__ __launch_bounds__(256) void k3(const float* __restrict__ Q,
    const float* __restrict__ cv, float* __restrict__ out)
{
  __shared__ float yt[CCH][HWB];               // [c][hw] tile, 32 KB
  const int b   = blockIdx.x / NHB;
  const int hb  = blockIdx.x % NHB;
  const int hw0 = hb * HWB;
  const int tid = threadIdx.x;
  #pragma unroll
  for(int it=0;it<8;it++){
    const int cc = (tid>>4) + 16*it;
    float4 v = *(const float4*)(out + ((size_t)b*CCH + cc)*HWD + hw0 + 4*(tid&15));
    *(float4*)(&yt[cc][4*(tid&15)]) = v;
  }
  __syncthreads();
  const int o0 = (tid & 15)*8;
  const int hg = (tid >> 4)*4;
  float acc[8][4];
  #pragma unroll
  for(int i=0;i<8;i++){ acc[i][0]=0.f; acc[i][1]=0.f; acc[i][2]=0.f; acc[i][3]=0.f; }
  const float* Qb = Q + (size_t)b*CCH*CCH;
  for(int c4=0;c4<32;c4++){
    float4 yv[4];
    #pragma unroll
    for(int mm=0;mm<4;mm++) yv[mm] = *(const float4*)(&yt[4*c4+mm][hg]);
    #pragma unroll
    for(int i=0;i<8;i++){
      float4 q4 = *(const float4*)(Qb + (size_t)(o0+i)*CCH + 4*c4);
      const float ql[4] = {q4.x,q4.y,q4.z,q4.w};
      #pragma unroll
      for(int mm=0;mm<4;mm++){
        acc[i][0]=fmaf(ql[mm],yv[mm].x,acc[i][0]);
        acc[i][1]=fmaf(ql[mm],yv[mm].y,acc[i][1]);
        acc[i][2]=fmaf(ql[mm],yv[mm].z,acc[i][2]);
        acc[i][3]=fmaf(ql[mm],yv[mm].w,acc[i][3]);
      }
    }
  }
  #pragma unroll
  for(int i=0;i<8;i++){
    const float c = cv[b*CCH + o0+i];
    float4 o4 = make_float4(acc[i][0]+c, acc[i][1]+c, acc[i][2]+c, acc[i][3]+c);
    *(float4*)(out + ((size_t)b*CCH + o0+i)*HWD + hw0 + hg) = o4;
  }
}

extern "C" void kernel_launch(void* const* d_in, const int* in_sizes, int n_in,
                              void* d_out, int out_size, void* d_ws, size_t ws_size,
                              hipStream_t stream) {
  const float* x  = (const float*)d_in[0];
  const float* wq = (const float*)d_in[1];
  const float* bq = (const float*)d_in[2];
  const float* wk = (const float*)d_in[3];
  const float* bk = (const float*)d_in[4];
  const float* wv = (const float*)d_in[5];
  const float* bv = (const float*)d_in[6];
  const float* wo = (const float*)d_in[7];
  const float* bo = (const float*)d_in[8];
  float* out = (float*)d_out;
  float* ws  = (float*)d_ws;

  // zero the atomic accumulators (S, r) each call
  hipMemsetAsync(ws + OFF_S, 0, (size_t)(OFF_A - OFF_S)*sizeof(float), stream);

  k1_stats<<<BB*NHB, 256, 0, stream>>>(x, ws+OFF_S, ws+OFF_R, out);
  k2a<<<64, 256, 0, stream>>>(ws+OFF_S, ws+OFF_R, wq, bq, wk, bk, bv,
                              ws+OFF_A, ws+OFF_AV);
  k2b<<<64, 256, 0, stream>>>(ws+OFF_A, wv, ws+OFF_M);
  k2c<<<64, 256, 0, stream>>>(ws+OFF_M, wo, bo, ws+OFF_AV, ws+OFF_Q, ws+OFF_CV);
  k3<<<BB*NHB, 256, 0, stream>>>(ws+OFF_Q, ws+OFF_CV, out);
}

// Round 2
// 208.974 us; speedup vs baseline: 2.3263x; 2.3263x over previous
//
#include <hip/hip_runtime.h>
#include <hip/hip_bf16.h>
#include <cstdint>

#define BB   8
#define CCH  128
#define NND  16
#define HWD  3136      // 56*56
#define LLT  50176     // 16*3136
#define HWB  64        // hw columns per block (k1/k3); 3136 = 49*64
#define NHB  49

// workspace layout (float offsets)
#define OFF_S   0                       // 8*128*128   Gram (atomics, zeroed)
#define OFF_R   131072                  // 8*128       row sums (atomics, zeroed)
#define OFF_M   132096                  // 8*128*128   M = A @ W_v
#define OFF_Q   263168                  // 8*128*128   Q = W_o @ M + I
#define OFF_AV  394240                  // 8*128       av = A @ b_v
#define OFF_CV  395264                  // 8*128       c = W_o av + b_o

typedef __attribute__((ext_vector_type(8)))  short bf16x8;   // 4 VGPRs: 8 bf16
typedef __attribute__((ext_vector_type(16))) float f32x16;   // 32x32 MFMA acc

__device__ __forceinline__ uint32_t fbits(float f){ union{float f;uint32_t u;}v; v.f=f; return v.u; }
__device__ __forceinline__ float bitsf(uint32_t u){ union{uint32_t u;float f;}v; v.u=u; return v.f; }

#define MFMA32(a,b,c) __builtin_amdgcn_mfma_f32_32x32x16_bf16((a),(b),(c),0,0,0)

// ---------------- k1: Gram via bf16 hi/lo MFMA + rowsum + Y(=mean_N x) ------
// grid (b, hw-chunk of 64). LDS fragments stored k-chunk-major:
// lds[kc][row][8] so ds_read_b128 across lanes is linear (0 bank conflicts).
__global__ __launch_bounds__(256,2) void k1_gram(const float* __restrict__ x,
    float* __restrict__ S, float* __restrict__ r, float* __restrict__ Y)
{
  __shared__ __align__(16) short lds_hi[8*128*8];   // 16 KB
  __shared__ __align__(16) short lds_lo[8*128*8];   // 16 KB
  const int b   = blockIdx.x / NHB;
  const int hb  = blockIdx.x % NHB;
  const int hw0 = hb * HWB;
  const int tid = threadIdx.x;
  const int lane = tid & 63, w = tid >> 6;          // wave id 0..3
  const int rr  = tid >> 1, h = tid & 1;            // staging: row, half
  const float* xb = x + (size_t)b*CCH*LLT + (size_t)rr*LLT + hw0 + 32*h;

  f32x16 acc[4];
  #pragma unroll
  for(int j=0;j<4;j++)
    #pragma unroll
    for(int e=0;e<16;e++) acc[j][e] = 0.f;
  float yac[32];
  #pragma unroll
  for(int i=0;i<32;i++) yac[i]=0.f;

  float4 v[8];
  #pragma unroll
  for(int u=0;u<8;u++) v[u] = *(const float4*)(xb + 4*u);   // n=0 preload

  for(int n=0;n<NND;n++){
    __syncthreads();                       // prior compute done reading LDS
    // ---- stage: truncate-split fp32 -> bf16 hi/lo, pack via v_perm ----
    #pragma unroll
    for(int c2=0;c2<4;c2++){
      int hwd[4], lwd[4];
      #pragma unroll
      for(int q=0;q<2;q++){
        const int u = 2*c2+q;
        const float x0=v[u].x, x1=v[u].y, x2=v[u].z, x3=v[u].w;
        const uint32_t a0=fbits(x0),a1=fbits(x1),a2=fbits(x2),a3=fbits(x3);
        hwd[2*q+0] = __builtin_amdgcn_perm(a1, a0, 0x07060302u);
        hwd[2*q+1] = __builtin_amdgcn_perm(a3, a2, 0x07060302u);
        const float l0 = x0 - bitsf(a0&0xFFFF0000u);
        const float l1 = x1 - bitsf(a1&0xFFFF0000u);
        const float l2 = x2 - bitsf(a2&0xFFFF0000u);
        const float l3 = x3 - bitsf(a3&0xFFFF0000u);
        lwd[2*q+0] = __builtin_amdgcn_perm(fbits(l1), fbits(l0), 0x07060302u);
        lwd[2*q+1] = __builtin_amdgcn_perm(fbits(l3), fbits(l2), 0x07060302u);
        yac[4*u+0]+=x0; yac[4*u+1]+=x1; yac[4*u+2]+=x2; yac[4*u+3]+=x3;
      }
      const int kc = 4*h + c2;
      *(int4*)&lds_hi[(kc*128 + rr)*8] = make_int4(hwd[0],hwd[1],hwd[2],hwd[3]);
      *(int4*)&lds_lo[(kc*128 + rr)*8] = make_int4(lwd[0],lwd[1],lwd[2],lwd[3]);
    }
    __syncthreads();
    if(n+1 < NND){                         // prefetch next n during compute
      #pragma unroll
      for(int u=0;u<8;u++) v[u] = *(const float4*)(xb + (n+1)*HWD + 4*u);
    }
    // ---- compute: 4 K-steps of 16, tiles (w, 0..3), hi/lo cross terms ----
    #pragma unroll
    for(int ks=0;ks<4;ks++){
      const int base8 = ((2*ks + (lane>>5))*128 + (lane&31))*8;
      const bf16x8 ah = *(const bf16x8*)&lds_hi[base8 + 256*w];
      const bf16x8 al = *(const bf16x8*)&lds_lo[base8 + 256*w];
      #pragma unroll
      for(int j=0;j<4;j++){
        const bf16x8 bh = *(const bf16x8*)&lds_hi[base8 + 256*j];
        const bf16x8 bl = *(const bf16x8*)&lds_lo[base8 + 256*j];
        acc[j] = MFMA32(ah, bh, acc[j]);
        acc[j] = MFMA32(ah, bl, acc[j]);
        acc[j] = MFMA32(al, bh, acc[j]);
      }
    }
  }
  // ---- epilogue: Y, r, S ----
  #pragma unroll
  for(int u=0;u<8;u++){
    float4 o4 = make_float4(yac[4*u]*0.0625f, yac[4*u+1]*0.0625f,
                            yac[4*u+2]*0.0625f, yac[4*u+3]*0.0625f);
    *(float4*)(Y + ((size_t)b*CCH + rr)*HWD + hw0 + 32*h + 4*u) = o4;
  }
  float p = 0.f;
  #pragma unroll
  for(int i=0;i<32;i++) p += yac[i];
  p += __shfl_xor(p, 1);
  if(h==0) atomicAdd(&r[b*CCH + rr], p);

  float* Sb = S + (size_t)b*CCH*CCH;
  const int col = lane & 31, rbase = 32*w + 4*(lane>>5);
  #pragma unroll
  for(int j=0;j<4;j++)
    #pragma unroll
    for(int reg=0;reg<16;reg++){
      const int row = rbase + (reg&3) + 8*(reg>>2);
      atomicAdd(&Sb[(size_t)row*CCH + 32*j + col], acc[j][reg]);
    }
}

// ------- k2ab: G = WqSWk^T + bias, softmax -> A (LDS), M = A@Wv, av = A@bv --
__global__ __launch_bounds__(256) void k2ab(const float* __restrict__ S, const float* __restrict__ r,
    const float* __restrict__ wq, const float* __restrict__ bq,
    const float* __restrict__ wk, const float* __restrict__ bk,
    const float* __restrict__ wv, const float* __restrict__ bv,
    float* __restrict__ M, float* __restrict__ av)
{
  __shared__ __align__(16) float t1[16][132];
  __shared__ float wrk_s[CCH];
  __shared__ float wrq_s[16];
  const int b   = blockIdx.x >> 3;
  const int r0  = (blockIdx.x & 7) * 16;
  const int tid = threadIdx.x;
  const float* Sb = S + (size_t)b*CCH*CCH;
  const float* rb = r + b*CCH;

  if(tid < CCH){
    float s = 0.f;
    for(int m=0;m<CCH;m++) s += wk[(size_t)tid*CCH+m]*rb[m];
    wrk_s[tid] = s;
  } else if(tid < CCH+16){
    const int rr2 = tid - CCH;
    float s = 0.f;
    for(int m=0;m<CCH;m++) s += wq[(size_t)(r0+rr2)*CCH+m]*rb[m];
    wrq_s[rr2] = s;
  }

  const int rr = tid >> 4;
  const int c0 = (tid & 15) * 8;
  { // T1 = W_q[rows] @ S
    float a8[8] = {0,0,0,0,0,0,0,0};
    const float* wqr = wq + (size_t)(r0+rr)*CCH;
    for(int m4=0;m4<32;m4++){
      float4 w4 = *(const float4*)(wqr + 4*m4);
      const float wl[4] = {w4.x,w4.y,w4.z,w4.w};
      #pragma unroll
      for(int mm=0;mm<4;mm++){
        const int m = 4*m4+mm;
        const float w = wl[mm];
        float4 s0 = *(const float4*)(Sb + (size_t)m*CCH + c0);
        float4 s1 = *(const float4*)(Sb + (size_t)m*CCH + c0 + 4);
        a8[0]=fmaf(w,s0.x,a8[0]); a8[1]=fmaf(w,s0.y,a8[1]);
        a8[2]=fmaf(w,s0.z,a8[2]); a8[3]=fmaf(w,s0.w,a8[3]);
        a8[4]=fmaf(w,s1.x,a8[4]); a8[5]=fmaf(w,s1.y,a8[5]);
        a8[6]=fmaf(w,s1.z,a8[6]); a8[7]=fmaf(w,s1.w,a8[7]);
      }
    }
    #pragma unroll
    for(int j=0;j<8;j++) t1[rr][c0+j] = a8[j];
  }
  __syncthreads();

  const int j0 = c0;
  float g[8] = {0,0,0,0,0,0,0,0};
  for(int c4=0;c4<32;c4++){
    float4 tv = *(const float4*)(&t1[rr][4*c4]);
    #pragma unroll
    for(int jj=0;jj<8;jj++){
      float4 w4 = *(const float4*)(wk + (size_t)(j0+jj)*CCH + 4*c4);
      g[jj]=fmaf(tv.x,w4.x,g[jj]); g[jj]=fmaf(tv.y,w4.y,g[jj]);
      g[jj]=fmaf(tv.z,w4.z,g[jj]); g[jj]=fmaf(tv.w,w4.w,g[jj]);
    }
  }
  const float bqr  = bq[r0+rr];
  const float wrqr = wrq_s[rr];
  #pragma unroll
  for(int jj=0;jj<8;jj++)
    g[jj] += wrqr*bk[j0+jj] + bqr*wrk_s[j0+jj] + (float)LLT*bqr*bk[j0+jj];

  float mx = g[0];
  #pragma unroll
  for(int jj=1;jj<8;jj++) mx = fmaxf(mx, g[jj]);
  #pragma unroll
  for(int s=1;s<16;s<<=1) mx = fmaxf(mx, __shfl_xor(mx, s, 16));
  float ex[8], sum=0.f;
  #pragma unroll
  for(int jj=0;jj<8;jj++){ ex[jj] = expf(g[jj]-mx); sum += ex[jj]; }
  #pragma unroll
  for(int s=1;s<16;s<<=1) sum += __shfl_xor(sum, s, 16);
  const float inv = 1.0f/sum;

  float pa = 0.f;
  #pragma unroll
  for(int jj=0;jj<8;jj++) pa += ex[jj]*inv*bv[j0+jj];
  #pragma unroll
  for(int s=1;s<16;s<<=1) pa += __shfl_xor(pa, s, 16);
  if((tid&15)==0) av[b*CCH + r0+rr] = pa;

  __syncthreads();                 // all t1 reads done
  #pragma unroll
  for(int jj=0;jj<8;jj++) t1[rr][j0+jj] = ex[jj]*inv;   // A rows in LDS
  __syncthreads();

  { // M[rr][c0..c0+7] = A[rr] @ Wv
    float a8[8] = {0,0,0,0,0,0,0,0};
    for(int k4=0;k4<32;k4++){
      float4 a4 = *(const float4*)(&t1[rr][4*k4]);
      const float al[4] = {a4.x,a4.y,a4.z,a4.w};
      #pragma unroll
      for(int kk=0;kk<4;kk++){
        const int k = 4*k4+kk;
        const float wgt = al[kk];
        float4 v0 = *(const float4*)(wv + (size_t)k*CCH + c0);
        float4 v1 = *(const float4*)(wv + (size_t)k*CCH + c0 + 4);
        a8[0]=fmaf(wgt,v0.x,a8[0]); a8[1]=fmaf(wgt,v0.y,a8[1]);
        a8[2]=fmaf(wgt,v0.z,a8[2]); a8[3]=fmaf(wgt,v0.w,a8[3]);
        a8[4]=fmaf(wgt,v1.x,a8[4]); a8[5]=fmaf(wgt,v1.y,a8[5]);
        a8[6]=fmaf(wgt,v1.z,a8[6]); a8[7]=fmaf(wgt,v1.w,a8[7]);
      }
    }
    float* Mr = M + ((size_t)b*CCH + r0+rr)*CCH + c0;
    *(float4*)(Mr  ) = make_float4(a8[0],a8[1],a8[2],a8[3]);
    *(float4*)(Mr+4) = make_float4(a8[4],a8[5],a8[6],a8[7]);
  }
}

// ---------------- k2c: Q = W_o @ M + I ;  c = W_o av + b_o ------------------
__global__ __launch_bounds__(256) void k2c(const float* __restrict__ M,
    const float* __restrict__ wo, const float* __restrict__ bo,
    const float* __restrict__ av, float* __restrict__ Q, float* __restrict__ cv)
{
  const int b  = blockIdx.x >> 3;
  const int o0 = (blockIdx.x & 7)*16;
  const int tid = threadIdx.x;
  const int rr = tid>>4, c0 = (tid&15)*8;
  const int o  = o0 + rr;
  const float* wor = wo + (size_t)o*CCH;
  const float* Mb  = M + (size_t)b*CCH*CCH;
  float a8[8] = {0,0,0,0,0,0,0,0};
  for(int m4=0;m4<32;m4++){
    float4 w4 = *(const float4*)(wor + 4*m4);
    const float wl[4] = {w4.x,w4.y,w4.z,w4.w};
    #pragma unroll
    for(int mm=0;mm<4;mm++){
      const int m = 4*m4+mm;
      const float w = wl[mm];
      float4 v0 = *(const float4*)(Mb + (size_t)m*CCH + c0);
      float4 v1 = *(const float4*)(Mb + (size_t)m*CCH + c0 + 4);
      a8[0]=fmaf(w,v0.x,a8[0]); a8[1]=fmaf(w,v0.y,a8[1]);
      a8[2]=fmaf(w,v0.z,a8[2]); a8[3]=fmaf(w,v0.w,a8[3]);
      a8[4]=fmaf(w,v1.x,a8[4]); a8[5]=fmaf(w,v1.y,a8[5]);
      a8[6]=fmaf(w,v1.z,a8[6]); a8[7]=fmaf(w,v1.w,a8[7]);
    }
  }
  #pragma unroll
  for(int j=0;j<8;j++) if(o == c0+j) a8[j] += 1.0f;   // +I (residual folded)
  float* Qr = Q + ((size_t)b*CCH + o)*CCH + c0;
  *(float4*)(Qr  ) = make_float4(a8[0],a8[1],a8[2],a8[3]);
  *(float4*)(Qr+4) = make_float4(a8[4],a8[5],a8[6],a8[7]);

  if(tid < 16){
    const int oo = o0 + tid;
    float s = 0.f;
    for(int m=0;m<CCH;m++) s += wo[(size_t)oo*CCH+m]*av[b*CCH+m];
    cv[b*CCH + oo] = s + bo[oo];
  }
}

// ---------------- k3: out = Q @ Y + c  (in place over Y kept in d_out) ------
__global__ __launch_bounds__(256) void k3(const float* __restrict__ Q,
    const float* __restrict__ cv, float* __restrict__ out)
{
  __shared__ __align__(16) float yt[CCH][HWB];          // 32 KB
  const int b   = blockIdx.x / NHB;
  const int hb  = blockIdx.x % NHB;
  const int hw0 = hb * HWB;
  const int tid = threadIdx.x;
  #pragma unroll
  for(int it=0;it<8;it++){
    const int cc = (tid>>4) + 16*it;
    float4 v = *(const float4*)(out + ((size_t)b*CCH + cc)*HWD + hw0 + 4*(tid&15));
    *(float4*)(&yt[cc][4*(tid&15)]) = v;
  }
  __syncthreads();
  const int o0 = (tid & 15)*8;
  const int hg = (tid >> 4)*4;
  float acc[8][4];
  #pragma unroll
  for(int i=0;i<8;i++){ acc[i][0]=0.f; acc[i][1]=0.f; acc[i][2]=0.f; acc[i][3]=0.f; }
  const float* Qb = Q + (size_t)b*CCH*CCH;
  for(int c4=0;c4<32;c4++){
    float4 yv[4];
    #pragma unroll
    for(int mm=0;mm<4;mm++) yv[mm] = *(const float4*)(&yt[4*c4+mm][hg]);
    #pragma unroll
    for(int i=0;i<8;i++){
      float4 q4 = *(const float4*)(Qb + (size_t)(o0+i)*CCH + 4*c4);
      const float ql[4] = {q4.x,q4.y,q4.z,q4.w};
      #pragma unroll
      for(int mm=0;mm<4;mm++){
        acc[i][0]=fmaf(ql[mm],yv[mm].x,acc[i][0]);
        acc[i][1]=fmaf(ql[mm],yv[mm].y,acc[i][1]);
        acc[i][2]=fmaf(ql[mm],yv[mm].z,acc[i][2]);
        acc[i][3]=fmaf(ql[mm],yv[mm].w,acc[i][3]);
      }
    }
  }
  #pragma unroll
  for(int i=0;i<8;i++){
    const float c = cv[b*CCH + o0+i];
    float4 o4 = make_float4(acc[i][0]+c, acc[i][1]+c, acc[i][2]+c, acc[i][3]+c);
    *(float4*)(out + ((size_t)b*CCH + o0+i)*HWD + hw0 + hg) = o4;
  }
}

extern "C" void kernel_launch(void* const* d_in, const int* in_sizes, int n_in,
                              void* d_out, int out_size, void* d_ws, size_t ws_size,
                              hipStream_t stream) {
  const float* x  = (const float*)d_in[0];
  const float* wq = (const float*)d_in[1];
  const float* bq = (const float*)d_in[2];
  const float* wk = (const float*)d_in[3];
  const float* bk = (const float*)d_in[4];
  const float* wv = (const float*)d_in[5];
  const float* bv = (const float*)d_in[6];
  const float* wo = (const float*)d_in[7];
  const float* bo = (const float*)d_in[8];
  float* out = (float*)d_out;
  float* ws  = (float*)d_ws;

  // zero the atomic accumulators (S, r) each call
  hipMemsetAsync(ws + OFF_S, 0, (size_t)(OFF_M - OFF_S)*sizeof(float), stream);

  k1_gram<<<BB*NHB, 256, 0, stream>>>(x, ws+OFF_S, ws+OFF_R, out);
  k2ab<<<64, 256, 0, stream>>>(ws+OFF_S, ws+OFF_R, wq, bq, wk, bk, wv, bv,
                               ws+OFF_M, ws+OFF_AV);
  k2c<<<64, 256, 0, stream>>>(ws+OFF_M, wo, bo, ws+OFF_AV, ws+OFF_Q, ws+OFF_CV);
  k3<<<BB*NHB, 256, 0, stream>>>(ws+OFF_Q, ws+OFF_CV, out);
}

// Round 3
// 199.944 us; speedup vs baseline: 2.4313x; 1.0452x over previous
//
#include <hip/hip_runtime.h>
#include <hip/hip_bf16.h>
#include <cstdint>

#define BB   8
#define CCH  128
#define NND  16
#define HWD  3136      // 56*56
#define LLT  50176     // 16*3136
#define HWB  64        // hw columns per block (k1/k3); 3136 = 49*64
#define NHB  49

// workspace layout (float offsets) — no zero-init required anywhere
#define OFF_SP  0                         // 8*49*16384  per-block Gram partials
#define OFF_RP  6422528                   // 8*49*128    per-block rowsum partials
#define OFF_S   6472704                   // 8*16384     reduced Gram
#define OFF_M   6603776                   // 8*16384     M = A @ W_v
#define OFF_Q   6734848                   // 8*16384     Q = W_o @ M + I
#define OFF_AV  6865920                   // 8*128       av = A @ b_v
#define OFF_CV  6866944                   // 8*128       c = W_o av + b_o

typedef __attribute__((ext_vector_type(8)))  short bf16x8;   // 4 VGPRs: 8 bf16
typedef __attribute__((ext_vector_type(16))) float f32x16;   // 32x32 MFMA acc

__device__ __forceinline__ uint32_t fbits(float f){ union{float f;uint32_t u;}v; v.f=f; return v.u; }
__device__ __forceinline__ float bitsf(uint32_t u){ union{uint32_t u;float f;}v; v.u=u; return v.f; }

#define MFMA32(a,b,c) __builtin_amdgcn_mfma_f32_32x32x16_bf16((a),(b),(c),0,0,0)

// ---------------- k1: Gram via bf16 hi/lo MFMA + rowsum + Y(=mean_N x) ------
// grid (b, hw-chunk of 64). LDS fragments stored k-chunk-major:
// lds[kc][row][8] so ds_read_b128 across lanes is linear (0 bank conflicts).
// Partials are written to Sp/rp (plain stores) — reduced by k1r / k2ab.
__global__ __launch_bounds__(256,2) void k1_gram(const float* __restrict__ x,
    float* __restrict__ Sp, float* __restrict__ rp, float* __restrict__ Y)
{
  __shared__ __align__(16) short lds_hi[8*128*8];   // 16 KB
  __shared__ __align__(16) short lds_lo[8*128*8];   // 16 KB
  const int b   = blockIdx.x / NHB;
  const int hb  = blockIdx.x % NHB;
  const int hw0 = hb * HWB;
  const int tid = threadIdx.x;
  const int lane = tid & 63, w = tid >> 6;          // wave id 0..3
  const int rr  = tid >> 1, h = tid & 1;            // staging: row, half
  const float* xb = x + (size_t)b*CCH*LLT + (size_t)rr*LLT + hw0 + 32*h;

  f32x16 acc[4];
  #pragma unroll
  for(int j=0;j<4;j++)
    #pragma unroll
    for(int e=0;e<16;e++) acc[j][e] = 0.f;
  float yac[32];
  #pragma unroll
  for(int i=0;i<32;i++) yac[i]=0.f;

  float4 v[8];
  #pragma unroll
  for(int u=0;u<8;u++) v[u] = *(const float4*)(xb + 4*u);   // n=0 preload

  for(int n=0;n<NND;n++){
    __syncthreads();                       // prior compute done reading LDS
    // ---- stage: truncate-split fp32 -> bf16 hi/lo, pack via v_perm ----
    #pragma unroll
    for(int c2=0;c2<4;c2++){
      int hwd[4], lwd[4];
      #pragma unroll
      for(int q=0;q<2;q++){
        const int u = 2*c2+q;
        const float x0=v[u].x, x1=v[u].y, x2=v[u].z, x3=v[u].w;
        const uint32_t a0=fbits(x0),a1=fbits(x1),a2=fbits(x2),a3=fbits(x3);
        hwd[2*q+0] = __builtin_amdgcn_perm(a1, a0, 0x07060302u);
        hwd[2*q+1] = __builtin_amdgcn_perm(a3, a2, 0x07060302u);
        const float l0 = x0 - bitsf(a0&0xFFFF0000u);
        const float l1 = x1 - bitsf(a1&0xFFFF0000u);
        const float l2 = x2 - bitsf(a2&0xFFFF0000u);
        const float l3 = x3 - bitsf(a3&0xFFFF0000u);
        lwd[2*q+0] = __builtin_amdgcn_perm(fbits(l1), fbits(l0), 0x07060302u);
        lwd[2*q+1] = __builtin_amdgcn_perm(fbits(l3), fbits(l2), 0x07060302u);
        yac[4*u+0]+=x0; yac[4*u+1]+=x1; yac[4*u+2]+=x2; yac[4*u+3]+=x3;
      }
      const int kc = 4*h + c2;
      *(int4*)&lds_hi[(kc*128 + rr)*8] = make_int4(hwd[0],hwd[1],hwd[2],hwd[3]);
      *(int4*)&lds_lo[(kc*128 + rr)*8] = make_int4(lwd[0],lwd[1],lwd[2],lwd[3]);
    }
    __syncthreads();
    if(n+1 < NND){                         // prefetch next n during compute
      #pragma unroll
      for(int u=0;u<8;u++) v[u] = *(const float4*)(xb + (n+1)*HWD + 4*u);
    }
    // ---- compute: 4 K-steps of 16, tiles (w, 0..3), hi/lo cross terms ----
    #pragma unroll
    for(int ks=0;ks<4;ks++){
      const int base8 = ((2*ks + (lane>>5))*128 + (lane&31))*8;
      const bf16x8 ah = *(const bf16x8*)&lds_hi[base8 + 256*w];
      const bf16x8 al = *(const bf16x8*)&lds_lo[base8 + 256*w];
      #pragma unroll
      for(int j=0;j<4;j++){
        const bf16x8 bh = *(const bf16x8*)&lds_hi[base8 + 256*j];
        const bf16x8 bl = *(const bf16x8*)&lds_lo[base8 + 256*j];
        acc[j] = MFMA32(ah, bh, acc[j]);
        acc[j] = MFMA32(ah, bl, acc[j]);
        acc[j] = MFMA32(al, bh, acc[j]);
      }
    }
  }
  // ---- epilogue: Y, r-partial, S-partial (plain stores) ----
  #pragma unroll
  for(int u=0;u<8;u++){
    float4 o4 = make_float4(yac[4*u]*0.0625f, yac[4*u+1]*0.0625f,
                            yac[4*u+2]*0.0625f, yac[4*u+3]*0.0625f);
    *(float4*)(Y + ((size_t)b*CCH + rr)*HWD + hw0 + 32*h + 4*u) = o4;
  }
  float p = 0.f;
  #pragma unroll
  for(int i=0;i<32;i++) p += yac[i];
  p += __shfl_xor(p, 1);
  if(h==0) rp[(size_t)(b*NHB+hb)*CCH + rr] = p;

  float* Sb = Sp + (size_t)(b*NHB+hb)*CCH*CCH;
  const int col = lane & 31, rbase = 32*w + 4*(lane>>5);
  #pragma unroll
  for(int j=0;j<4;j++)
    #pragma unroll
    for(int reg=0;reg<16;reg++){
      const int row = rbase + (reg&3) + 8*(reg>>2);
      Sb[(size_t)row*CCH + 32*j + col] = acc[j][reg];
    }
}

// ---------------- k1r: S[b] = sum_hb Sp[b,hb] -------------------------------
__global__ __launch_bounds__(256) void k1r(const float* __restrict__ Sp,
                                           float* __restrict__ S)
{
  const int b  = blockIdx.x >> 4;
  const int ch = blockIdx.x & 15;
  const int i  = ch*1024 + threadIdx.x*4;
  const float* p = Sp + (size_t)b*NHB*CCH*CCH + i;
  float4 s = make_float4(0.f,0.f,0.f,0.f);
  for(int hb=0;hb<NHB;hb++){
    float4 v = *(const float4*)(p + (size_t)hb*CCH*CCH);
    s.x+=v.x; s.y+=v.y; s.z+=v.z; s.w+=v.w;
  }
  *(float4*)(S + (size_t)b*CCH*CCH + i) = s;
}

// ------- k2ab: G = WqSWk^T + bias, softmax -> A (LDS), M = A@Wv, av = A@bv --
__global__ __launch_bounds__(256) void k2ab(const float* __restrict__ S, const float* __restrict__ rp,
    const float* __restrict__ wq, const float* __restrict__ bq,
    const float* __restrict__ wk, const float* __restrict__ bk,
    const float* __restrict__ wv, const float* __restrict__ bv,
    float* __restrict__ M, float* __restrict__ av)
{
  __shared__ __align__(16) float t1[16][132];
  __shared__ float rb_s[CCH];
  __shared__ float wrk_s[CCH];
  __shared__ float wrq_s[16];
  const int b   = blockIdx.x >> 3;
  const int r0  = (blockIdx.x & 7) * 16;
  const int tid = threadIdx.x;
  const float* Sb = S + (size_t)b*CCH*CCH;

  if(tid < CCH){          // reduce rowsum partials for this batch
    float s = 0.f;
    const float* rpb = rp + (size_t)b*NHB*CCH + tid;
    for(int hb=0;hb<NHB;hb++) s += rpb[hb*CCH];
    rb_s[tid] = s;
  }
  __syncthreads();

  if(tid < CCH){
    float s = 0.f;
    for(int m=0;m<CCH;m++) s += wk[(size_t)tid*CCH+m]*rb_s[m];
    wrk_s[tid] = s;
  } else if(tid < CCH+16){
    const int rr2 = tid - CCH;
    float s = 0.f;
    for(int m=0;m<CCH;m++) s += wq[(size_t)(r0+rr2)*CCH+m]*rb_s[m];
    wrq_s[rr2] = s;
  }

  const int rr = tid >> 4;
  const int c0 = (tid & 15) * 8;
  { // T1 = W_q[rows] @ S
    float a8[8] = {0,0,0,0,0,0,0,0};
    const float* wqr = wq + (size_t)(r0+rr)*CCH;
    for(int m4=0;m4<32;m4++){
      float4 w4 = *(const float4*)(wqr + 4*m4);
      const float wl[4] = {w4.x,w4.y,w4.z,w4.w};
      #pragma unroll
      for(int mm=0;mm<4;mm++){
        const int m = 4*m4+mm;
        const float w = wl[mm];
        float4 s0 = *(const float4*)(Sb + (size_t)m*CCH + c0);
        float4 s1 = *(const float4*)(Sb + (size_t)m*CCH + c0 + 4);
        a8[0]=fmaf(w,s0.x,a8[0]); a8[1]=fmaf(w,s0.y,a8[1]);
        a8[2]=fmaf(w,s0.z,a8[2]); a8[3]=fmaf(w,s0.w,a8[3]);
        a8[4]=fmaf(w,s1.x,a8[4]); a8[5]=fmaf(w,s1.y,a8[5]);
        a8[6]=fmaf(w,s1.z,a8[6]); a8[7]=fmaf(w,s1.w,a8[7]);
      }
    }
    #pragma unroll
    for(int j=0;j<8;j++) t1[rr][c0+j] = a8[j];
  }
  __syncthreads();

  const int j0 = c0;
  float g[8] = {0,0,0,0,0,0,0,0};
  for(int c4=0;c4<32;c4++){
    float4 tv = *(const float4*)(&t1[rr][4*c4]);
    #pragma unroll
    for(int jj=0;jj<8;jj++){
      float4 w4 = *(const float4*)(wk + (size_t)(j0+jj)*CCH + 4*c4);
      g[jj]=fmaf(tv.x,w4.x,g[jj]); g[jj]=fmaf(tv.y,w4.y,g[jj]);
      g[jj]=fmaf(tv.z,w4.z,g[jj]); g[jj]=fmaf(tv.w,w4.w,g[jj]);
    }
  }
  const float bqr  = bq[r0+rr];
  const float wrqr = wrq_s[rr];
  #pragma unroll
  for(int jj=0;jj<8;jj++)
    g[jj] += wrqr*bk[j0+jj] + bqr*wrk_s[j0+jj] + (float)LLT*bqr*bk[j0+jj];

  float mx = g[0];
  #pragma unroll
  for(int jj=1;jj<8;jj++) mx = fmaxf(mx, g[jj]);
  #pragma unroll
  for(int s=1;s<16;s<<=1) mx = fmaxf(mx, __shfl_xor(mx, s, 16));
  float ex[8], sum=0.f;
  #pragma unroll
  for(int jj=0;jj<8;jj++){ ex[jj] = expf(g[jj]-mx); sum += ex[jj]; }
  #pragma unroll
  for(int s=1;s<16;s<<=1) sum += __shfl_xor(sum, s, 16);
  const float inv = 1.0f/sum;

  float pa = 0.f;
  #pragma unroll
  for(int jj=0;jj<8;jj++) pa += ex[jj]*inv*bv[j0+jj];
  #pragma unroll
  for(int s=1;s<16;s<<=1) pa += __shfl_xor(pa, s, 16);
  if((tid&15)==0) av[b*CCH + r0+rr] = pa;

  __syncthreads();                 // all t1 reads done
  #pragma unroll
  for(int jj=0;jj<8;jj++) t1[rr][j0+jj] = ex[jj]*inv;   // A rows in LDS
  __syncthreads();

  { // M[rr][c0..c0+7] = A[rr] @ Wv
    float a8[8] = {0,0,0,0,0,0,0,0};
    for(int k4=0;k4<32;k4++){
      float4 a4 = *(const float4*)(&t1[rr][4*k4]);
      const float al[4] = {a4.x,a4.y,a4.z,a4.w};
      #pragma unroll
      for(int kk=0;kk<4;kk++){
        const int k = 4*k4+kk;
        const float wgt = al[kk];
        float4 v0 = *(const float4*)(wv + (size_t)k*CCH + c0);
        float4 v1 = *(const float4*)(wv + (size_t)k*CCH + c0 + 4);
        a8[0]=fmaf(wgt,v0.x,a8[0]); a8[1]=fmaf(wgt,v0.y,a8[1]);
        a8[2]=fmaf(wgt,v0.z,a8[2]); a8[3]=fmaf(wgt,v0.w,a8[3]);
        a8[4]=fmaf(wgt,v1.x,a8[4]); a8[5]=fmaf(wgt,v1.y,a8[5]);
        a8[6]=fmaf(wgt,v1.z,a8[6]); a8[7]=fmaf(wgt,v1.w,a8[7]);
      }
    }
    float* Mr = M + ((size_t)b*CCH + r0+rr)*CCH + c0;
    *(float4*)(Mr  ) = make_float4(a8[0],a8[1],a8[2],a8[3]);
    *(float4*)(Mr+4) = make_float4(a8[4],a8[5],a8[6],a8[7]);
  }
}

// ---------------- k2c: Q = W_o @ M + I ;  c = W_o av + b_o ------------------
__global__ __launch_bounds__(256) void k2c(const float* __restrict__ M,
    const float* __restrict__ wo, const float* __restrict__ bo,
    const float* __restrict__ av, float* __restrict__ Q, float* __restrict__ cv)
{
  const int b  = blockIdx.x >> 3;
  const int o0 = (blockIdx.x & 7)*16;
  const int tid = threadIdx.x;
  const int rr = tid>>4, c0 = (tid&15)*8;
  const int o  = o0 + rr;
  const float* wor = wo + (size_t)o*CCH;
  const float* Mb  = M + (size_t)b*CCH*CCH;
  float a8[8] = {0,0,0,0,0,0,0,0};
  for(int m4=0;m4<32;m4++){
    float4 w4 = *(const float4*)(wor + 4*m4);
    const float wl[4] = {w4.x,w4.y,w4.z,w4.w};
    #pragma unroll
    for(int mm=0;mm<4;mm++){
      const int m = 4*m4+mm;
      const float w = wl[mm];
      float4 v0 = *(const float4*)(Mb + (size_t)m*CCH + c0);
      float4 v1 = *(const float4*)(Mb + (size_t)m*CCH + c0 + 4);
      a8[0]=fmaf(w,v0.x,a8[0]); a8[1]=fmaf(w,v0.y,a8[1]);
      a8[2]=fmaf(w,v0.z,a8[2]); a8[3]=fmaf(w,v0.w,a8[3]);
      a8[4]=fmaf(w,v1.x,a8[4]); a8[5]=fmaf(w,v1.y,a8[5]);
      a8[6]=fmaf(w,v1.z,a8[6]); a8[7]=fmaf(w,v1.w,a8[7]);
    }
  }
  #pragma unroll
  for(int j=0;j<8;j++) if(o == c0+j) a8[j] += 1.0f;   // +I (residual folded)
  float* Qr = Q + ((size_t)b*CCH + o)*CCH + c0;
  *(float4*)(Qr  ) = make_float4(a8[0],a8[1],a8[2],a8[3]);
  *(float4*)(Qr+4) = make_float4(a8[4],a8[5],a8[6],a8[7]);

  if(tid < 16){
    const int oo = o0 + tid;
    float s = 0.f;
    for(int m=0;m<CCH;m++) s += wo[(size_t)oo*CCH+m]*av[b*CCH+m];
    cv[b*CCH + oo] = s + bo[oo];
  }
}

// ---------------- k3: out = Q @ Y + c  (in place over Y kept in d_out) ------
__global__ __launch_bounds__(256) void k3(const float* __restrict__ Q,
    const float* __restrict__ cv, float* __restrict__ out)
{
  __shared__ __align__(16) float yt[CCH][HWB];          // 32 KB
  const int b   = blockIdx.x / NHB;
  const int hb  = blockIdx.x % NHB;
  const int hw0 = hb * HWB;
  const int tid = threadIdx.x;
  #pragma unroll
  for(int it=0;it<8;it++){
    const int cc = (tid>>4) + 16*it;
    float4 v = *(const float4*)(out + ((size_t)b*CCH + cc)*HWD + hw0 + 4*(tid&15));
    *(float4*)(&yt[cc][4*(tid&15)]) = v;
  }
  __syncthreads();
  const int o0 = (tid & 15)*8;
  const int hg = (tid >> 4)*4;
  float acc[8][4];
  #pragma unroll
  for(int i=0;i<8;i++){ acc[i][0]=0.f; acc[i][1]=0.f; acc[i][2]=0.f; acc[i][3]=0.f; }
  const float* Qb = Q + (size_t)b*CCH*CCH;
  for(int c4=0;c4<32;c4++){
    float4 yv[4];
    #pragma unroll
    for(int mm=0;mm<4;mm++) yv[mm] = *(const float4*)(&yt[4*c4+mm][hg]);
    #pragma unroll
    for(int i=0;i<8;i++){
      float4 q4 = *(const float4*)(Qb + (size_t)(o0+i)*CCH + 4*c4);
      const float ql[4] = {q4.x,q4.y,q4.z,q4.w};
      #pragma unroll
      for(int mm=0;mm<4;mm++){
        acc[i][0]=fmaf(ql[mm],yv[mm].x,acc[i][0]);
        acc[i][1]=fmaf(ql[mm],yv[mm].y,acc[i][1]);
        acc[i][2]=fmaf(ql[mm],yv[mm].z,acc[i][2]);
        acc[i][3]=fmaf(ql[mm],yv[mm].w,acc[i][3]);
      }
    }
  }
  #pragma unroll
  for(int i=0;i<8;i++){
    const float c = cv[b*CCH + o0+i];
    float4 o4 = make_float4(acc[i][0]+c, acc[i][1]+c, acc[i][2]+c, acc[i][3]+c);
    *(float4*)(out + ((size_t)b*CCH + o0+i)*HWD + hw0 + hg) = o4;
  }
}

extern "C" void kernel_launch(void* const* d_in, const int* in_sizes, int n_in,
                              void* d_out, int out_size, void* d_ws, size_t ws_size,
                              hipStream_t stream) {
  const float* x  = (const float*)d_in[0];
  const float* wq = (const float*)d_in[1];
  const float* bq = (const float*)d_in[2];
  const float* wk = (const float*)d_in[3];
  const float* bk = (const float*)d_in[4];
  const float* wv = (const float*)d_in[5];
  const float* bv = (const float*)d_in[6];
  const float* wo = (const float*)d_in[7];
  const float* bo = (const float*)d_in[8];
  float* out = (float*)d_out;
  float* ws  = (float*)d_ws;

  k1_gram<<<BB*NHB, 256, 0, stream>>>(x, ws+OFF_SP, ws+OFF_RP, out);
  k1r<<<128, 256, 0, stream>>>(ws+OFF_SP, ws+OFF_S);
  k2ab<<<64, 256, 0, stream>>>(ws+OFF_S, ws+OFF_RP, wq, bq, wk, bk, wv, bv,
                               ws+OFF_M, ws+OFF_AV);
  k2c<<<64, 256, 0, stream>>>(ws+OFF_M, wo, bo, ws+OFF_AV, ws+OFF_Q, ws+OFF_CV);
  k3<<<BB*NHB, 256, 0, stream>>>(ws+OFF_Q, ws+OFF_CV, out);
}

// Round 4
// 145.942 us; speedup vs baseline: 3.3310x; 1.3700x over previous
//
#include <hip/hip_runtime.h>
#include <hip/hip_bf16.h>
#include <cstdint>

#define BB   8
#define CCH  128
#define NND  16
#define HWD  3136      // 56*56
#define LLT  50176     // 16*3136
#define HWB  64        // hw columns per block (k1/k3); 3136 = 49*64
#define NHB  49

// workspace layout (float offsets) — no zero-init required anywhere
#define OFF_SP  0                         // 8*49*16384  per-block Gram partials
#define OFF_RP  6422528                   // 8*49*128    per-block rowsum partials
#define OFF_S   6472704                   // 8*16384     reduced Gram
#define OFF_M   6603776                   // 8*16384     M = A @ W_v
#define OFF_Q   6734848                   // 8*16384     Q = W_o @ M + I
#define OFF_AV  6865920                   // 8*128       av = A @ b_v
#define OFF_CV  6866944                   // 8*128       c = W_o av + b_o

typedef __attribute__((ext_vector_type(8)))  short bf16x8;   // 4 VGPRs: 8 bf16
typedef __attribute__((ext_vector_type(16))) float f32x16;   // 32x32 MFMA acc

__device__ __forceinline__ uint32_t fbits(float f){ union{float f;uint32_t u;}v; v.f=f; return v.u; }
__device__ __forceinline__ float bitsf(uint32_t u){ union{uint32_t u;float f;}v; v.u=u; return v.f; }

#define MFMA32(a,b,c) __builtin_amdgcn_mfma_f32_32x32x16_bf16((a),(b),(c),0,0,0)

// ---------------- k1: Gram via bf16 hi/lo MFMA + rowsum + Y(=mean_N x) ------
// Double-buffered LDS (one barrier per plane), 2x2 wave tiling.
__global__ __launch_bounds__(256,2) void k1_gram(const float* __restrict__ x,
    float* __restrict__ Sp, float* __restrict__ rp, float* __restrict__ Y)
{
  __shared__ __align__(16) short lds_h[2][8*128*8];   // 2 x 16 KB
  __shared__ __align__(16) short lds_l[2][8*128*8];   // 2 x 16 KB
  const int b   = blockIdx.x / NHB;
  const int hb  = blockIdx.x % NHB;
  const int hw0 = hb * HWB;
  const int tid = threadIdx.x;
  const int lane = tid & 63, w = tid >> 6;            // wave id 0..3
  const int wr = w >> 1, wc = w & 1;                  // 2x2 wave tiling
  const int rr  = tid >> 1, h = tid & 1;              // staging: row, half
  const float* xb = x + (size_t)b*CCH*LLT + (size_t)rr*LLT + hw0 + 32*h;

  f32x16 acc[2][2];
  #pragma unroll
  for(int ai=0;ai<2;ai++)
    #pragma unroll
    for(int bi=0;bi<2;bi++)
      #pragma unroll
      for(int e=0;e<16;e++) acc[ai][bi][e] = 0.f;
  float yac[32];
  #pragma unroll
  for(int i=0;i<32;i++) yac[i]=0.f;

  float4 v[8];
  #pragma unroll
  for(int u=0;u<8;u++) v[u] = *(const float4*)(xb + 4*u);   // plane 0

  // SPLIT of plane held in v -> buffer bufi (also accumulates yac)
#define SPLIT(bufi)                                                         \
  {                                                                         \
    _Pragma("unroll")                                                       \
    for(int c2=0;c2<4;c2++){                                                \
      int hwd_[4], lwd_[4];                                                 \
      _Pragma("unroll")                                                     \
      for(int q=0;q<2;q++){                                                 \
        const int u = 2*c2+q;                                               \
        const float x0=v[u].x, x1=v[u].y, x2=v[u].z, x3=v[u].w;             \
        const uint32_t a0=fbits(x0),a1=fbits(x1),a2=fbits(x2),a3=fbits(x3); \
        hwd_[2*q+0] = __builtin_amdgcn_perm(a1, a0, 0x07060302u);           \
        hwd_[2*q+1] = __builtin_amdgcn_perm(a3, a2, 0x07060302u);           \
        const float l0 = x0 - bitsf(a0&0xFFFF0000u);                        \
        const float l1 = x1 - bitsf(a1&0xFFFF0000u);                        \
        const float l2 = x2 - bitsf(a2&0xFFFF0000u);                        \
        const float l3 = x3 - bitsf(a3&0xFFFF0000u);                        \
        lwd_[2*q+0] = __builtin_amdgcn_perm(fbits(l1), fbits(l0), 0x07060302u); \
        lwd_[2*q+1] = __builtin_amdgcn_perm(fbits(l3), fbits(l2), 0x07060302u); \
        yac[4*u+0]+=x0; yac[4*u+1]+=x1; yac[4*u+2]+=x2; yac[4*u+3]+=x3;     \
      }                                                                     \
      const int kc = 4*h + c2;                                              \
      *(int4*)&lds_h[bufi][(kc*128 + rr)*8] = make_int4(hwd_[0],hwd_[1],hwd_[2],hwd_[3]); \
      *(int4*)&lds_l[bufi][(kc*128 + rr)*8] = make_int4(lwd_[0],lwd_[1],lwd_[2],lwd_[3]); \
    }                                                                       \
  }

  SPLIT(0);
  __syncthreads();
  #pragma unroll
  for(int u=0;u<8;u++) v[u] = *(const float4*)(xb + HWD + 4*u);  // plane 1

  for(int n=0;n<NND;n++){
    const int cur = n & 1;
    // ---- compute plane n from buf[cur] ----
    #pragma unroll
    for(int ks=0;ks<4;ks++){
      const int kc = 2*ks + (lane>>5);
      const int rbase = (kc*128 + (lane&31))*8;
      const bf16x8 a0h = *(const bf16x8*)&lds_h[cur][rbase + (64*wr    )*8];
      const bf16x8 a0l = *(const bf16x8*)&lds_l[cur][rbase + (64*wr    )*8];
      const bf16x8 a1h = *(const bf16x8*)&lds_h[cur][rbase + (64*wr+32)*8];
      const bf16x8 a1l = *(const bf16x8*)&lds_l[cur][rbase + (64*wr+32)*8];
      const bf16x8 b0h = *(const bf16x8*)&lds_h[cur][rbase + (64*wc    )*8];
      const bf16x8 b0l = *(const bf16x8*)&lds_l[cur][rbase + (64*wc    )*8];
      const bf16x8 b1h = *(const bf16x8*)&lds_h[cur][rbase + (64*wc+32)*8];
      const bf16x8 b1l = *(const bf16x8*)&lds_l[cur][rbase + (64*wc+32)*8];
      acc[0][0] = MFMA32(a0h, b0h, acc[0][0]);
      acc[0][0] = MFMA32(a0h, b0l, acc[0][0]);
      acc[0][0] = MFMA32(a0l, b0h, acc[0][0]);
      acc[0][1] = MFMA32(a0h, b1h, acc[0][1]);
      acc[0][1] = MFMA32(a0h, b1l, acc[0][1]);
      acc[0][1] = MFMA32(a0l, b1h, acc[0][1]);
      acc[1][0] = MFMA32(a1h, b0h, acc[1][0]);
      acc[1][0] = MFMA32(a1h, b0l, acc[1][0]);
      acc[1][0] = MFMA32(a1l, b0h, acc[1][0]);
      acc[1][1] = MFMA32(a1h, b1h, acc[1][1]);
      acc[1][1] = MFMA32(a1h, b1l, acc[1][1]);
      acc[1][1] = MFMA32(a1l, b1h, acc[1][1]);
    }
    // ---- stage plane n+1 (v holds it), then prefetch plane n+2 ----
    if(n+1 < NND){
      SPLIT(cur^1);
      __syncthreads();
      if(n+2 < NND){
        #pragma unroll
        for(int u=0;u<8;u++) v[u] = *(const float4*)(xb + (size_t)(n+2)*HWD + 4*u);
      }
    }
  }
#undef SPLIT

  // ---- epilogue: Y, r-partial, S-partial (plain stores) ----
  #pragma unroll
  for(int u=0;u<8;u++){
    float4 o4 = make_float4(yac[4*u]*0.0625f, yac[4*u+1]*0.0625f,
                            yac[4*u+2]*0.0625f, yac[4*u+3]*0.0625f);
    *(float4*)(Y + ((size_t)b*CCH + rr)*HWD + hw0 + 32*h + 4*u) = o4;
  }
  float p = 0.f;
  #pragma unroll
  for(int i=0;i<32;i++) p += yac[i];
  p += __shfl_xor(p, 1);
  if(h==0) rp[(size_t)(b*NHB+hb)*CCH + rr] = p;

  float* Sb = Sp + (size_t)(b*NHB+hb)*CCH*CCH;
  const int col = lane & 31, roff = 4*(lane>>5);
  #pragma unroll
  for(int ai=0;ai<2;ai++)
    #pragma unroll
    for(int bi=0;bi<2;bi++)
      #pragma unroll
      for(int reg=0;reg<16;reg++){
        const int row = 64*wr + 32*ai + roff + (reg&3) + 8*(reg>>2);
        Sb[(size_t)row*CCH + 64*wc + 32*bi + col] = acc[ai][bi][reg];
      }
}

// ---------------- k1r: S[b] = sum_hb Sp[b,hb] -------------------------------
__global__ __launch_bounds__(256) void k1r(const float* __restrict__ Sp,
                                           float* __restrict__ S)
{
  const int b  = blockIdx.x >> 4;
  const int ch = blockIdx.x & 15;
  const int i  = ch*1024 + threadIdx.x*4;
  const float* p = Sp + (size_t)b*NHB*CCH*CCH + i;
  float4 s = make_float4(0.f,0.f,0.f,0.f);
  for(int hb=0;hb<NHB;hb++){
    float4 v = *(const float4*)(p + (size_t)hb*CCH*CCH);
    s.x+=v.x; s.y+=v.y; s.z+=v.z; s.w+=v.w;
  }
  *(float4*)(S + (size_t)b*CCH*CCH + i) = s;
}

// ------- k2ab: G = WqSWk^T + bias, softmax -> A (LDS), M = A@Wv, av = A@bv --
__global__ __launch_bounds__(256) void k2ab(const float* __restrict__ S, const float* __restrict__ rp,
    const float* __restrict__ wq, const float* __restrict__ bq,
    const float* __restrict__ wk, const float* __restrict__ bk,
    const float* __restrict__ wv, const float* __restrict__ bv,
    float* __restrict__ M, float* __restrict__ av)
{
  __shared__ __align__(16) float t1[16][132];
  __shared__ float rb_s[CCH];
  __shared__ float wrk_s[CCH];
  __shared__ float wrq_s[16];
  const int b   = blockIdx.x >> 3;
  const int r0  = (blockIdx.x & 7) * 16;
  const int tid = threadIdx.x;
  const float* Sb = S + (size_t)b*CCH*CCH;

  if(tid < CCH){          // reduce rowsum partials for this batch
    float s = 0.f;
    const float* rpb = rp + (size_t)b*NHB*CCH + tid;
    for(int hb=0;hb<NHB;hb++) s += rpb[hb*CCH];
    rb_s[tid] = s;
  }
  __syncthreads();

  if(tid < CCH){
    float s = 0.f;
    for(int m=0;m<CCH;m++) s += wk[(size_t)tid*CCH+m]*rb_s[m];
    wrk_s[tid] = s;
  } else if(tid < CCH+16){
    const int rr2 = tid - CCH;
    float s = 0.f;
    for(int m=0;m<CCH;m++) s += wq[(size_t)(r0+rr2)*CCH+m]*rb_s[m];
    wrq_s[rr2] = s;
  }

  const int rr = tid >> 4;
  const int c0 = (tid & 15) * 8;
  { // T1 = W_q[rows] @ S
    float a8[8] = {0,0,0,0,0,0,0,0};
    const float* wqr = wq + (size_t)(r0+rr)*CCH;
    for(int m4=0;m4<32;m4++){
      float4 w4 = *(const float4*)(wqr + 4*m4);
      const float wl[4] = {w4.x,w4.y,w4.z,w4.w};
      #pragma unroll
      for(int mm=0;mm<4;mm++){
        const int m = 4*m4+mm;
        const float w = wl[mm];
        float4 s0 = *(const float4*)(Sb + (size_t)m*CCH + c0);
        float4 s1 = *(const float4*)(Sb + (size_t)m*CCH + c0 + 4);
        a8[0]=fmaf(w,s0.x,a8[0]); a8[1]=fmaf(w,s0.y,a8[1]);
        a8[2]=fmaf(w,s0.z,a8[2]); a8[3]=fmaf(w,s0.w,a8[3]);
        a8[4]=fmaf(w,s1.x,a8[4]); a8[5]=fmaf(w,s1.y,a8[5]);
        a8[6]=fmaf(w,s1.z,a8[6]); a8[7]=fmaf(w,s1.w,a8[7]);
      }
    }
    #pragma unroll
    for(int j=0;j<8;j++) t1[rr][c0+j] = a8[j];
  }
  __syncthreads();

  const int j0 = c0;
  float g[8] = {0,0,0,0,0,0,0,0};
  for(int c4=0;c4<32;c4++){
    float4 tv = *(const float4*)(&t1[rr][4*c4]);
    #pragma unroll
    for(int jj=0;jj<8;jj++){
      float4 w4 = *(const float4*)(wk + (size_t)(j0+jj)*CCH + 4*c4);
      g[jj]=fmaf(tv.x,w4.x,g[jj]); g[jj]=fmaf(tv.y,w4.y,g[jj]);
      g[jj]=fmaf(tv.z,w4.z,g[jj]); g[jj]=fmaf(tv.w,w4.w,g[jj]);
    }
  }
  const float bqr  = bq[r0+rr];
  const float wrqr = wrq_s[rr];
  #pragma unroll
  for(int jj=0;jj<8;jj++)
    g[jj] += wrqr*bk[j0+jj] + bqr*wrk_s[j0+jj] + (float)LLT*bqr*bk[j0+jj];

  float mx = g[0];
  #pragma unroll
  for(int jj=1;jj<8;jj++) mx = fmaxf(mx, g[jj]);
  #pragma unroll
  for(int s=1;s<16;s<<=1) mx = fmaxf(mx, __shfl_xor(mx, s, 16));
  float ex[8], sum=0.f;
  #pragma unroll
  for(int jj=0;jj<8;jj++){ ex[jj] = expf(g[jj]-mx); sum += ex[jj]; }
  #pragma unroll
  for(int s=1;s<16;s<<=1) sum += __shfl_xor(sum, s, 16);
  const float inv = 1.0f/sum;

  float pa = 0.f;
  #pragma unroll
  for(int jj=0;jj<8;jj++) pa += ex[jj]*inv*bv[j0+jj];
  #pragma unroll
  for(int s=1;s<16;s<<=1) pa += __shfl_xor(pa, s, 16);
  if((tid&15)==0) av[b*CCH + r0+rr] = pa;

  __syncthreads();                 // all t1 reads done
  #pragma unroll
  for(int jj=0;jj<8;jj++) t1[rr][j0+jj] = ex[jj]*inv;   // A rows in LDS
  __syncthreads();

  { // M[rr][c0..c0+7] = A[rr] @ Wv
    float a8[8] = {0,0,0,0,0,0,0,0};
    for(int k4=0;k4<32;k4++){
      float4 a4 = *(const float4*)(&t1[rr][4*k4]);
      const float al[4] = {a4.x,a4.y,a4.z,a4.w};
      #pragma unroll
      for(int kk=0;kk<4;kk++){
        const int k = 4*k4+kk;
        const float wgt = al[kk];
        float4 v0 = *(const float4*)(wv + (size_t)k*CCH + c0);
        float4 v1 = *(const float4*)(wv + (size_t)k*CCH + c0 + 4);
        a8[0]=fmaf(wgt,v0.x,a8[0]); a8[1]=fmaf(wgt,v0.y,a8[1]);
        a8[2]=fmaf(wgt,v0.z,a8[2]); a8[3]=fmaf(wgt,v0.w,a8[3]);
        a8[4]=fmaf(wgt,v1.x,a8[4]); a8[5]=fmaf(wgt,v1.y,a8[5]);
        a8[6]=fmaf(wgt,v1.z,a8[6]); a8[7]=fmaf(wgt,v1.w,a8[7]);
      }
    }
    float* Mr = M + ((size_t)b*CCH + r0+rr)*CCH + c0;
    *(float4*)(Mr  ) = make_float4(a8[0],a8[1],a8[2],a8[3]);
    *(float4*)(Mr+4) = make_float4(a8[4],a8[5],a8[6],a8[7]);
  }
}

// ---------------- k2c: Q = W_o @ M + I ;  c = W_o av + b_o ------------------
__global__ __launch_bounds__(256) void k2c(const float* __restrict__ M,
    const float* __restrict__ wo, const float* __restrict__ bo,
    const float* __restrict__ av, float* __restrict__ Q, float* __restrict__ cv)
{
  const int b  = blockIdx.x >> 3;
  const int o0 = (blockIdx.x & 7)*16;
  const int tid = threadIdx.x;
  const int rr = tid>>4, c0 = (tid&15)*8;
  const int o  = o0 + rr;
  const float* wor = wo + (size_t)o*CCH;
  const float* Mb  = M + (size_t)b*CCH*CCH;
  float a8[8] = {0,0,0,0,0,0,0,0};
  for(int m4=0;m4<32;m4++){
    float4 w4 = *(const float4*)(wor + 4*m4);
    const float wl[4] = {w4.x,w4.y,w4.z,w4.w};
    #pragma unroll
    for(int mm=0;mm<4;mm++){
      const int m = 4*m4+mm;
      const float w = wl[mm];
      float4 v0 = *(const float4*)(Mb + (size_t)m*CCH + c0);
      float4 v1 = *(const float4*)(Mb + (size_t)m*CCH + c0 + 4);
      a8[0]=fmaf(w,v0.x,a8[0]); a8[1]=fmaf(w,v0.y,a8[1]);
      a8[2]=fmaf(w,v0.z,a8[2]); a8[3]=fmaf(w,v0.w,a8[3]);
      a8[4]=fmaf(w,v1.x,a8[4]); a8[5]=fmaf(w,v1.y,a8[5]);
      a8[6]=fmaf(w,v1.z,a8[6]); a8[7]=fmaf(w,v1.w,a8[7]);
    }
  }
  #pragma unroll
  for(int j=0;j<8;j++) if(o == c0+j) a8[j] += 1.0f;   // +I (residual folded)
  float* Qr = Q + ((size_t)b*CCH + o)*CCH + c0;
  *(float4*)(Qr  ) = make_float4(a8[0],a8[1],a8[2],a8[3]);
  *(float4*)(Qr+4) = make_float4(a8[4],a8[5],a8[6],a8[7]);

  if(tid < 16){
    const int oo = o0 + tid;
    float s = 0.f;
    for(int m=0;m<CCH;m++) s += wo[(size_t)oo*CCH+m]*av[b*CCH+m];
    cv[b*CCH + oo] = s + bo[oo];
  }
}

// ---------------- k3: out = Q @ Y + c  (in place; Q staged in LDS) ----------
// Q in LDS as float4 chunks with XOR swizzle: phys = (row<<5) | (chunk ^ (row>>3))
__global__ __launch_bounds__(256,2) void k3(const float* __restrict__ Q,
    const float* __restrict__ cv, float* __restrict__ out)
{
  __shared__ __align__(16) float4 qs[4096];             // 64 KB
  const int b   = blockIdx.x / NHB;
  const int hb  = blockIdx.x % NHB;
  const int hw0 = hb * HWB;
  const int tid = threadIdx.x;

  const float4* Qg = (const float4*)(Q + (size_t)b*CCH*CCH);
  #pragma unroll
  for(int it=0; it<16; it++){
    const int idx = it*256 + tid;          // float4 index 0..4095
    const int row = idx >> 5, ch = idx & 31;
    qs[(row<<5) | (ch ^ (row>>3))] = Qg[idx];
  }
  __syncthreads();

  const int tx = tid & 15, ty = tid >> 4;
  const int o0 = tx*8;                      // output-channel base (8 rows)
  const int hg = ty*4;                      // hw offset (4 cols)
  float acc[8][4];
  #pragma unroll
  for(int i=0;i<8;i++){ acc[i][0]=0.f; acc[i][1]=0.f; acc[i][2]=0.f; acc[i][3]=0.f; }

  const float* Yb = out + (size_t)b*CCH*HWD + hw0 + hg;
  for(int c4=0;c4<32;c4++){
    float4 yv[4];
    #pragma unroll
    for(int mm=0;mm<4;mm++) yv[mm] = *(const float4*)(Yb + (size_t)(4*c4+mm)*HWD);
    #pragma unroll
    for(int i=0;i<8;i++){
      const int row = o0 + i;               // row>>3 == tx (i<8)
      const float4 q4 = qs[(row<<5) | (c4 ^ tx)];
      const float ql[4] = {q4.x,q4.y,q4.z,q4.w};
      #pragma unroll
      for(int mm=0;mm<4;mm++){
        acc[i][0]=fmaf(ql[mm],yv[mm].x,acc[i][0]);
        acc[i][1]=fmaf(ql[mm],yv[mm].y,acc[i][1]);
        acc[i][2]=fmaf(ql[mm],yv[mm].z,acc[i][2]);
        acc[i][3]=fmaf(ql[mm],yv[mm].w,acc[i][3]);
      }
    }
  }
  __syncthreads();                          // all Y reads done before overwrite
  #pragma unroll
  for(int i=0;i<8;i++){
    const float c = cv[b*CCH + o0+i];
    float4 o4 = make_float4(acc[i][0]+c, acc[i][1]+c, acc[i][2]+c, acc[i][3]+c);
    *(float4*)(out + ((size_t)b*CCH + o0+i)*HWD + hw0 + hg) = o4;
  }
}

extern "C" void kernel_launch(void* const* d_in, const int* in_sizes, int n_in,
                              void* d_out, int out_size, void* d_ws, size_t ws_size,
                              hipStream_t stream) {
  const float* x  = (const float*)d_in[0];
  const float* wq = (const float*)d_in[1];
  const float* bq = (const float*)d_in[2];
  const float* wk = (const float*)d_in[3];
  const float* bk = (const float*)d_in[4];
  const float* wv = (const float*)d_in[5];
  const float* bv = (const float*)d_in[6];
  const float* wo = (const float*)d_in[7];
  const float* bo = (const float*)d_in[8];
  float* out = (float*)d_out;
  float* ws  = (float*)d_ws;

  k1_gram<<<BB*NHB, 256, 0, stream>>>(x, ws+OFF_SP, ws+OFF_RP, out);
  k1r<<<128, 256, 0, stream>>>(ws+OFF_SP, ws+OFF_S);
  k2ab<<<64, 256, 0, stream>>>(ws+OFF_S, ws+OFF_RP, wq, bq, wk, bk, wv, bv,
                               ws+OFF_M, ws+OFF_AV);
  k2c<<<64, 256, 0, stream>>>(ws+OFF_M, wo, bo, ws+OFF_AV, ws+OFF_Q, ws+OFF_CV);
  k3<<<BB*NHB, 256, 0, stream>>>(ws+OFF_Q, ws+OFF_CV, out);
}